// Round 2
// baseline (840.745 us; speedup 1.0000x reference)
//
#include <hip/hip_runtime.h>

// Child-Sum Tree-LSTM fused kernel, MI355X/gfx950. Round 2.
// Split-fp32-into-bf16(hi,lo), 3x MFMA per logical tile for ~fp32 accuracy.
// R2 changes vs R1: software-pipelined child loop (prefetch h_{k+1}, c_k into
// registers during GEMM_k), double-buffered Hk LDS (1 barrier/child), and
// GEMM3 folded into the child GEMMs (h_sum@U_iou == sum_k h_k@U_iou).

#define NN 131072          // nodes
#define LDSS 136           // LDS row stride in bf16 elems (128 + 8 pad)

typedef __attribute__((ext_vector_type(8))) short bf16x8;
typedef __attribute__((ext_vector_type(4))) float f32x4;

// d_ws layout, in ushort (bf16) units. Weights pre-split + pre-swizzled to MFMA-B fragment order.
#define BX_HI 0            // [W_iou | W_f] : 128 x 512
#define BX_LO 65536
#define BH_HI 131072       // U_iou : 128 x 384
#define BH_LO 180224
#define UF_HI 229376       // U_f : 128 x 128
#define UF_LO 245760

__device__ __forceinline__ unsigned short f2bf(float f){
  unsigned int u = __float_as_uint(f);
  u += 0x7FFFu + ((u >> 16) & 1u);   // round-to-nearest-even
  return (unsigned short)(u >> 16);
}
__device__ __forceinline__ float bf2f(unsigned short h){
  return __uint_as_float(((unsigned int)h) << 16);
}
__device__ __forceinline__ float sigm(float v){ return 1.f / (1.f + __expf(-v)); }
__device__ __forceinline__ float tanh_f(float v){
  float a = fabsf(v);
  float e = __expf(-2.f * a);
  float r = (1.f - e) / (1.f + e);
  return copysignf(r, v);
}

__device__ __forceinline__ void split8_store(unsigned short* hp, unsigned short* lp,
                                             const float* v){
  unsigned short h[8], l[8];
#pragma unroll
  for (int i = 0; i < 8; ++i){
    h[i] = f2bf(v[i]);
    l[i] = f2bf(v[i] - bf2f(h[i]));
  }
  uint4 uh, ul;
  uh.x = (unsigned)h[0] | ((unsigned)h[1] << 16);
  uh.y = (unsigned)h[2] | ((unsigned)h[3] << 16);
  uh.z = (unsigned)h[4] | ((unsigned)h[5] << 16);
  uh.w = (unsigned)h[6] | ((unsigned)h[7] << 16);
  ul.x = (unsigned)l[0] | ((unsigned)l[1] << 16);
  ul.y = (unsigned)l[2] | ((unsigned)l[3] << 16);
  ul.z = (unsigned)l[4] | ((unsigned)l[5] << 16);
  ul.w = (unsigned)l[6] | ((unsigned)l[7] << 16);
  *(uint4*)hp = uh;
  *(uint4*)lp = ul;
}

// ---- prep: split weights to hi/lo bf16, swizzled into MFMA-B fragment order ----
__global__ void prep_weights(const float* __restrict__ Wiou, const float* __restrict__ Uiou,
                             const float* __restrict__ Wf, const float* __restrict__ Uf,
                             unsigned short* __restrict__ ws){
  int tid = blockIdx.x * 256 + threadIdx.x;  // 0 .. 131071
  float v; int k, col, nt; unsigned int bhi, blo;
  if (tid < 65536){                       // Bx: 128 x 512 = [W_iou | W_f]
    k = tid >> 9; col = tid & 511;
    v = (col < 384) ? Wiou[k * 384 + col] : Wf[k * 128 + (col - 384)];
    nt = 32; bhi = BX_HI; blo = BX_LO;
  } else if (tid < 65536 + 49152){        // Bh: 128 x 384 = U_iou
    int s = tid - 65536; k = s / 384; col = s - k * 384;
    v = Uiou[k * 384 + col];
    nt = 24; bhi = BH_HI; blo = BH_LO;
  } else {                                // Uf: 128 x 128
    int s = tid - 65536 - 49152; k = s >> 7; col = s & 127;
    v = Uf[k * 128 + col];
    nt = 8; bhi = UF_HI; blo = UF_LO;
  }
  int kc = k >> 5, q = (k >> 3) & 3, j = k & 7;
  int nc = col >> 4, cc = col & 15;
  int lane = q * 16 + cc;
  unsigned int addr = ((unsigned)(kc * nt + nc) * 64u + (unsigned)lane) * 8u + (unsigned)j;
  unsigned short hi = f2bf(v);
  unsigned short lo = f2bf(v - bf2f(hi));
  ws[bhi + addr] = hi;
  ws[blo + addr] = lo;
}

// ---- main fused kernel ----
// block = 256 threads (4 waves), M = 32 nodes/block.
// Wave w owns features [32w, 32w+32) for every gate -> all state stays in-wave.
__launch_bounds__(256, 2)
__global__ void tree_lstm_fused(const float* __restrict__ xg,
                                const float* __restrict__ hcg,
                                const float* __restrict__ ccg,
                                const float* __restrict__ b_iou,
                                const float* __restrict__ b_f,
                                const unsigned short* __restrict__ ws,
                                float* __restrict__ out){
  __shared__ alignas(16) unsigned short AxHi[32 * LDSS];
  __shared__ alignas(16) unsigned short AxLo[32 * LDSS];
  __shared__ alignas(16) unsigned short HkHi[2][32 * LDSS];
  __shared__ alignas(16) unsigned short HkLo[2][32 * LDSS];

  const int t = threadIdx.x;
  const int lane = t & 63;
  const int w = t >> 6;          // wave 0..3
  const int m = lane & 15;       // A-frag row / C col (feature)
  const int q = lane >> 4;       // quad
  const int node0 = blockIdx.x * 32;
  const int nc0 = 2 * w;
  const int srow = t >> 4;       // staging row 0..15
  const int scol = (t & 15) * 8; // staging col (8 floats)

  // ---- issue x loads + child-0 prefetch (all in flight together) ----
  const float4* xp0 = (const float4*)(xg + (size_t)(node0 + srow) * 128 + scol);
  const float4* xp1 = (const float4*)(xg + (size_t)(node0 + 16 + srow) * 128 + scol);
  float4 x0a = xp0[0], x0b = xp0[1];
  float4 x1a = xp1[0], x1b = xp1[1];
  float4 pv0a, pv0b, pv1a, pv1b;
  {
    const float4* hp0 = (const float4*)(hcg + ((size_t)(node0 + srow) * 4 + 0) * 128 + scol);
    const float4* hp1 = (const float4*)(hcg + ((size_t)(node0 + 16 + srow) * 4 + 0) * 128 + scol);
    pv0a = hp0[0]; pv0b = hp0[1]; pv1a = hp1[0]; pv1b = hp1[1];
  }
  float bfv[2];
  bfv[0] = b_f[w * 32 + m];
  bfv[1] = b_f[w * 32 + 16 + m];

  // ---- stage x tile as hi/lo bf16 ----
  {
    float v[8] = {x0a.x, x0a.y, x0a.z, x0a.w, x0b.x, x0b.y, x0b.z, x0b.w};
    split8_store(AxHi + srow * LDSS + scol, AxLo + srow * LDSS + scol, v);
  }
  {
    float v[8] = {x1a.x, x1a.y, x1a.z, x1a.w, x1b.x, x1b.y, x1b.z, x1b.w};
    split8_store(AxHi + (16 + srow) * LDSS + scol, AxLo + (16 + srow) * LDSS + scol, v);
  }
  __syncthreads();

  // ---- GEMM1: x @ [W_iou | W_f] -> acc[c][rt], c = gate*2+sub, gates {i,o,u,xWf} ----
  const f32x4 zero = {0.f, 0.f, 0.f, 0.f};
  f32x4 acc[8][2];
#pragma unroll
  for (int c = 0; c < 8; ++c)
#pragma unroll
    for (int rt = 0; rt < 2; ++rt) acc[c][rt] = zero;

#pragma unroll
  for (int kc = 0; kc < 4; ++kc){
    bf16x8 ah[2], al[2];
#pragma unroll
    for (int rt = 0; rt < 2; ++rt){
      int off = (rt * 16 + m) * LDSS + kc * 32 + q * 8;
      ah[rt] = *(const bf16x8*)(AxHi + off);
      al[rt] = *(const bf16x8*)(AxLo + off);
    }
#pragma unroll
    for (int c = 0; c < 8; ++c){
      int nc = (c >> 1) * 8 + nc0 + (c & 1);
      bf16x8 bh = *(const bf16x8*)(ws + BX_HI + ((kc * 32 + nc) * 64 + lane) * 8);
      bf16x8 bl = *(const bf16x8*)(ws + BX_LO + ((kc * 32 + nc) * 64 + lane) * 8);
#pragma unroll
      for (int rt = 0; rt < 2; ++rt){
        acc[c][rt] = __builtin_amdgcn_mfma_f32_16x16x32_bf16(ah[rt], bh, acc[c][rt], 0, 0, 0);
        acc[c][rt] = __builtin_amdgcn_mfma_f32_16x16x32_bf16(al[rt], bh, acc[c][rt], 0, 0, 0);
        acc[c][rt] = __builtin_amdgcn_mfma_f32_16x16x32_bf16(ah[rt], bl, acc[c][rt], 0, 0, 0);
      }
    }
  }

  // ---- children: GEMM over [U_iou | U_f] per child (iou accumulated directly),
  //      fused forget-gate epilogue. Software-pipelined. ----
  f32x4 fc[2][2];
#pragma unroll
  for (int ct = 0; ct < 2; ++ct)
#pragma unroll
    for (int rt = 0; rt < 2; ++rt) fc[ct][rt] = zero;

#pragma unroll
  for (int k = 0; k < 4; ++k){
    // write prefetched child k into LDS buffer k&1
    {
      float v[8] = {pv0a.x, pv0a.y, pv0a.z, pv0a.w, pv0b.x, pv0b.y, pv0b.z, pv0b.w};
      split8_store(HkHi[k & 1] + srow * LDSS + scol, HkLo[k & 1] + srow * LDSS + scol, v);
    }
    {
      float v[8] = {pv1a.x, pv1a.y, pv1a.z, pv1a.w, pv1b.x, pv1b.y, pv1b.z, pv1b.w};
      split8_store(HkHi[k & 1] + (16 + srow) * LDSS + scol,
                   HkLo[k & 1] + (16 + srow) * LDSS + scol, v);
    }
    __syncthreads();

    // prefetch child k+1 h (overlaps GEMM below)
    if (k < 3){
      const float4* hp0 = (const float4*)(hcg + ((size_t)(node0 + srow) * 4 + (k + 1)) * 128 + scol);
      const float4* hp1 = (const float4*)(hcg + ((size_t)(node0 + 16 + srow) * 4 + (k + 1)) * 128 + scol);
      pv0a = hp0[0]; pv0b = hp0[1]; pv1a = hp1[0]; pv1b = hp1[1];
    }
    // prefetch c_child(k) (consumed in this child's epilogue, loads overlap GEMM)
    float cpre[16];
#pragma unroll
    for (int ct = 0; ct < 2; ++ct)
#pragma unroll
      for (int rt = 0; rt < 2; ++rt)
#pragma unroll
        for (int r = 0; r < 4; ++r)
          cpre[(ct * 2 + rt) * 4 + r] =
              ccg[((size_t)(node0 + rt * 16 + q * 4 + r) * 4 + k) * 128 + w * 32 + ct * 16 + m];

    f32x4 hu[2][2];
#pragma unroll
    for (int ct = 0; ct < 2; ++ct)
#pragma unroll
      for (int rt = 0; rt < 2; ++rt) hu[ct][rt] = zero;

#pragma unroll
    for (int kc = 0; kc < 4; ++kc){
      bf16x8 ah[2], al[2];
#pragma unroll
      for (int rt = 0; rt < 2; ++rt){
        int off = (rt * 16 + m) * LDSS + kc * 32 + q * 8;
        ah[rt] = *(const bf16x8*)(HkHi[k & 1] + off);
        al[rt] = *(const bf16x8*)(HkLo[k & 1] + off);
      }
      // U_iou slices -> accumulate straight into iou accumulators
#pragma unroll
      for (int g = 0; g < 3; ++g){
#pragma unroll
        for (int ct = 0; ct < 2; ++ct){
          int nc = g * 8 + nc0 + ct;
          bf16x8 bh = *(const bf16x8*)(ws + BH_HI + ((kc * 24 + nc) * 64 + lane) * 8);
          bf16x8 bl = *(const bf16x8*)(ws + BH_LO + ((kc * 24 + nc) * 64 + lane) * 8);
#pragma unroll
          for (int rt = 0; rt < 2; ++rt){
            acc[g*2+ct][rt] = __builtin_amdgcn_mfma_f32_16x16x32_bf16(ah[rt], bh, acc[g*2+ct][rt], 0, 0, 0);
            acc[g*2+ct][rt] = __builtin_amdgcn_mfma_f32_16x16x32_bf16(al[rt], bh, acc[g*2+ct][rt], 0, 0, 0);
            acc[g*2+ct][rt] = __builtin_amdgcn_mfma_f32_16x16x32_bf16(ah[rt], bl, acc[g*2+ct][rt], 0, 0, 0);
          }
        }
      }
      // U_f slice -> per-child hu
#pragma unroll
      for (int ct = 0; ct < 2; ++ct){
        int nc = nc0 + ct;
        bf16x8 bh = *(const bf16x8*)(ws + UF_HI + ((kc * 8 + nc) * 64 + lane) * 8);
        bf16x8 bl = *(const bf16x8*)(ws + UF_LO + ((kc * 8 + nc) * 64 + lane) * 8);
#pragma unroll
        for (int rt = 0; rt < 2; ++rt){
          hu[ct][rt] = __builtin_amdgcn_mfma_f32_16x16x32_bf16(ah[rt], bh, hu[ct][rt], 0, 0, 0);
          hu[ct][rt] = __builtin_amdgcn_mfma_f32_16x16x32_bf16(al[rt], bh, hu[ct][rt], 0, 0, 0);
          hu[ct][rt] = __builtin_amdgcn_mfma_f32_16x16x32_bf16(ah[rt], bl, hu[ct][rt], 0, 0, 0);
        }
      }
    }
    // fused forget gate: fc += sigmoid(xWf + h_k U_f + b_f) * c_child_k
#pragma unroll
    for (int ct = 0; ct < 2; ++ct){
#pragma unroll
      for (int rt = 0; rt < 2; ++rt){
#pragma unroll
        for (int r = 0; r < 4; ++r){
          float pre = acc[6 + ct][rt][r] + hu[ct][rt][r] + bfv[ct];
          fc[ct][rt][r] += sigm(pre) * cpre[(ct * 2 + rt) * 4 + r];
        }
      }
    }
  }

  // ---- final epilogue: gates + store h, c ----
  float biv[2], bov[2], buv[2];
#pragma unroll
  for (int ct = 0; ct < 2; ++ct){
    int f = w * 32 + ct * 16 + m;
    biv[ct] = b_iou[f];
    bov[ct] = b_iou[128 + f];
    buv[ct] = b_iou[256 + f];
  }
#pragma unroll
  for (int ct = 0; ct < 2; ++ct){
    int f = w * 32 + ct * 16 + m;
#pragma unroll
    for (int rt = 0; rt < 2; ++rt){
#pragma unroll
      for (int r = 0; r < 4; ++r){
        int node = node0 + rt * 16 + q * 4 + r;
        float iv = sigm(acc[ct][rt][r] + biv[ct]);
        float ov = sigm(acc[2 + ct][rt][r] + bov[ct]);
        float uv = tanh_f(acc[4 + ct][rt][r] + buv[ct]);
        float cv = iv * uv + fc[ct][rt][r];
        float hv = ov * tanh_f(cv);
        out[(size_t)node * 128 + f] = hv;
        out[(size_t)NN * 128 + (size_t)node * 128 + f] = cv;
      }
    }
  }
}

extern "C" void kernel_launch(void* const* d_in, const int* in_sizes, int n_in,
                              void* d_out, int out_size, void* d_ws, size_t ws_size,
                              hipStream_t stream){
  const float* x       = (const float*)d_in[0];
  const float* h_child = (const float*)d_in[1];
  const float* c_child = (const float*)d_in[2];
  const float* W_iou   = (const float*)d_in[3];
  const float* U_iou   = (const float*)d_in[4];
  const float* b_iou   = (const float*)d_in[5];
  const float* W_f     = (const float*)d_in[6];
  const float* U_f     = (const float*)d_in[7];
  const float* b_f     = (const float*)d_in[8];
  unsigned short* ws   = (unsigned short*)d_ws;
  float* out           = (float*)d_out;

  prep_weights<<<512, 256, 0, stream>>>(W_iou, U_iou, W_f, U_f, ws);
  tree_lstm_fused<<<NN / 32, 256, 0, stream>>>(x, h_child, c_child, b_iou, b_f, ws, out);
}